// Round 22
// baseline (67.053 us; speedup 1.0000x reference)
//
#include <hip/hip_runtime.h>
#include <hip/hip_fp16.h>

typedef _Float16 half_t;
typedef _Float16 f16x8 __attribute__((ext_vector_type(8)));
typedef __fp16 fp16x2 __attribute__((ext_vector_type(2)));
typedef float f32x4 __attribute__((ext_vector_type(4)));

#define MFMA_F16(a, b, c) __builtin_amdgcn_mfma_f32_16x16x32_f16((a), (b), (c), 0, 0, 0)

static __device__ inline unsigned pkrtz(float a, float b) {
    union { fp16x2 h; unsigned u; } c;
    c.h = __builtin_amdgcn_cvt_pkrtz(a, b);
    return c.u;
}

// ---------------------------------------------------------------------------
// prep (80 blocks):
//   0..47 : Wt = (rw@qw)^T fp16 [768][512]; q-cols scaled by 0.125*log2(e)
//   48..79: pw_t = proj_w^T fp16 [512][256]
// ---------------------------------------------------------------------------
__global__ __launch_bounds__(256) void prep(
    const float* __restrict__ qw, const float* __restrict__ rw,
    const float* __restrict__ pw, half_t* __restrict__ pw_t,
    half_t* __restrict__ Wt) {
    __shared__ __align__(16) char smem[24576];
    const int bid = blockIdx.x, tid = threadIdx.x;

    if (bid < 48) {
        char* As = smem;
        char* Bs = smem + 8192;
        const int M0 = (bid % 12) * 64, N0 = (bid / 12) * 128;
        const int lane = tid & 63, w = tid >> 6;
        const int l15 = lane & 15, l4 = lane >> 4;
        const int wrow = (w >> 1) * 32, wcol = (w & 1) * 64;
        const int pa = (l15 & 7) << 4;

        f32x4 acc[2][4];
#pragma unroll
        for (int i = 0; i < 2; ++i)
#pragma unroll
            for (int j = 0; j < 4; ++j) acc[i][j] = (f32x4){0.f, 0.f, 0.f, 0.f};

        for (int kc = 0; kc < 4; ++kc) {
            int c0 = kc * 64;
            __syncthreads();
#pragma unroll
            for (int i = 0; i < 2; ++i) {
                int j = tid + i * 256;
                int row = j >> 3, e8 = (j & 7) * 8;
                float s = (M0 + row) < 256 ? 0.18033688f : 1.f;  // 0.125*log2e
                f16x8 v;
#pragma unroll
                for (int e = 0; e < 8; ++e)
                    v[e] = (half_t)(qw[(size_t)(c0 + e8 + e) * 768 + M0 + row] * s);
                *(f16x8*)(As + row * 128 + ((e8 * 2) ^ ((row & 7) << 4))) = v;
            }
#pragma unroll
            for (int i = 0; i < 4; ++i) {
                int j = tid + i * 256;
                int row = j >> 3, e8 = (j & 7) * 8;
                const float* p = rw + (size_t)(N0 + row) * 256 + c0 + e8;
                float4 u0 = *(const float4*)p;
                float4 u1 = *(const float4*)(p + 4);
                f16x8 v;
                v[0] = (half_t)u0.x; v[1] = (half_t)u0.y;
                v[2] = (half_t)u0.z; v[3] = (half_t)u0.w;
                v[4] = (half_t)u1.x; v[5] = (half_t)u1.y;
                v[6] = (half_t)u1.z; v[7] = (half_t)u1.w;
                *(f16x8*)(Bs + row * 128 + ((e8 * 2) ^ ((row & 7) << 4))) = v;
            }
            __syncthreads();
#pragma unroll
            for (int ki = 0; ki < 2; ++ki) {
                f16x8 af[2], bf[4];
#pragma unroll
                for (int mi = 0; mi < 2; ++mi) {
                    int row = wrow + mi * 16 + l15;
                    af[mi] = *(const f16x8*)(As + row * 128 + (((ki * 4 + l4) << 4) ^ pa));
                }
#pragma unroll
                for (int nj = 0; nj < 4; ++nj) {
                    int row = wcol + nj * 16 + l15;
                    bf[nj] = *(const f16x8*)(Bs + row * 128 + (((ki * 4 + l4) << 4) ^ pa));
                }
#pragma unroll
                for (int mi = 0; mi < 2; ++mi)
#pragma unroll
                    for (int nj = 0; nj < 4; ++nj)
                        acc[mi][nj] = MFMA_F16(af[mi], bf[nj], acc[mi][nj]);
            }
        }
#pragma unroll
        for (int mi = 0; mi < 2; ++mi)
#pragma unroll
            for (int nj = 0; nj < 4; ++nj)
#pragma unroll
                for (int reg = 0; reg < 4; ++reg) {
                    int grow = M0 + wrow + mi * 16 + l4 * 4 + reg;
                    int gcol = N0 + wcol + nj * 16 + l15;
                    Wt[(size_t)grow * 512 + gcol] = (half_t)acc[mi][nj][reg];
                }
        return;
    }

    // pw transpose
    half_t* tile = (half_t*)smem;  // [64][72]
    int t = bid - 48;
    int R0 = (t >> 3) * 64, C0 = (t & 7) * 64;
#pragma unroll
    for (int e = 0; e < 16; ++e) {
        int idx = tid + e * 256;
        int r = idx >> 6, c = idx & 63;
        tile[r * 72 + c] = (half_t)pw[(size_t)(R0 + r) * 512 + C0 + c];
    }
    __syncthreads();
#pragma unroll
    for (int e = 0; e < 16; ++e) {
        int idx = tid + e * 256;
        int c = idx >> 6, r = idx & 63;
        pw_t[(size_t)(C0 + c) * 256 + R0 + r] = tile[r * 72 + c];
    }
}

// ---------------------------------------------------------------------------
// fp16 MFMA GEMM, single-barrier double-buffered reg-staged engine:
//   load_reg(0);
//   for kt: { store_tile(buf[kt&1]);   // regs (tile kt) -> LDS
//             __syncthreads();         // writes visible, one barrier/K-step
//             load_reg(kt+1);          // globals fly across compute phase
//             compute(buf[kt&1]); }
// Hazards: store buf[kt&1] vs reads in iter kt-2 separated by iter kt-1's
// barrier; own-iteration reads after barrier; loads consumed by next
// iteration's store (waitcnt there, after a full compute phase of cover).
// BM=128, BN=NB, BK=64, 512 thr = 8 waves (2M x 4N), wave tile 64 x NB/4.
// LDS 2 x (16KB + NB*128B): 80KB @NB=192, 64KB @NB=128 -> 2 WG/CU.
// AFP32: A read fp32 + RTE cvt in reg (x used directly, no x_h pass).
// EPI 1: scatter q/k/v row-major [t][blk][key][dd]
// EPI 2: float out[grow*512+gcol] = acc + bias[gcol]
// ---------------------------------------------------------------------------
template <int EPI, bool AFP32, int NB, int K>
__global__ __launch_bounds__(512) void gemm_f16(
    const void* __restrict__ Aop, const half_t* __restrict__ Bt,
    void* __restrict__ Dst, const float* __restrict__ bias) {
    constexpr int nkt = K >> 6;
    constexpr int NAC = 2;          // A chunk groups
    constexpr int NBC = NB / 64;    // B chunk groups
    constexpr int NJ = NB / 64;     // B frags per wave
    constexpr int BUFSZ = 16384 + NB * 128;
    __shared__ __align__(16) char smem[2 * BUFSZ];

    const int tid = threadIdx.x;
    const int lane = tid & 63, w = tid >> 6;
    const int l15 = lane & 15, l4 = lane >> 4;
    const int wrow = (w >> 2) * 64;
    const int wcol = (w & 3) * (NB / 4);
    const int bm0 = blockIdx.x * 128;
    const int bn0 = blockIdx.y * NB;
    const int pa = (l15 & 7) << 4;

    f32x4 acc[4][NJ];
#pragma unroll
    for (int i = 0; i < 4; ++i)
#pragma unroll
        for (int j = 0; j < NJ; ++j) acc[i][j] = (f32x4){0.f, 0.f, 0.f, 0.f};

    f16x8 aReg[NAC], bReg[NBC];

    auto load_tile = [&](int kt) {
#pragma unroll
        for (int i = 0; i < NAC; ++i) {
            int c = tid + i * 512;
            int row = c >> 3, k0 = (c & 7) * 8;
            int gk = kt * 64 + k0;
            if (AFP32) {
                const float* Af = (const float*)Aop + (size_t)(bm0 + row) * K + gk;
                float4 u0 = *(const float4*)Af;
                float4 u1 = *(const float4*)(Af + 4);
                f16x8 v;
                v[0] = (half_t)u0.x; v[1] = (half_t)u0.y;
                v[2] = (half_t)u0.z; v[3] = (half_t)u0.w;
                v[4] = (half_t)u1.x; v[5] = (half_t)u1.y;
                v[6] = (half_t)u1.z; v[7] = (half_t)u1.w;
                aReg[i] = v;
            } else {
                aReg[i] = *(const f16x8*)((const half_t*)Aop + (size_t)(bm0 + row) * K + gk);
            }
        }
#pragma unroll
        for (int i = 0; i < NBC; ++i) {
            int c = tid + i * 512;
            int row = c >> 3, k0 = (c & 7) * 8;
            bReg[i] = *(const f16x8*)(Bt + (size_t)(bn0 + row) * K + kt * 64 + k0);
        }
    };

    load_tile(0);
    for (int kt = 0; kt < nkt; ++kt) {
        char* As = smem + (kt & 1) * BUFSZ;
        char* Bs = As + 16384;
        // store tile kt (in regs) to its buffer
#pragma unroll
        for (int i = 0; i < NAC; ++i) {
            int c = tid + i * 512;
            int row = c >> 3, k0 = (c & 7) * 8;
            *(f16x8*)(As + row * 128 + ((k0 * 2) ^ ((row & 7) << 4))) = aReg[i];
        }
#pragma unroll
        for (int i = 0; i < NBC; ++i) {
            int c = tid + i * 512;
            int row = c >> 3, k0 = (c & 7) * 8;
            *(f16x8*)(Bs + row * 128 + ((k0 * 2) ^ ((row & 7) << 4))) = bReg[i];
        }
        __syncthreads();                  // single barrier per K-step
        if (kt + 1 < nkt) load_tile(kt + 1);  // fly across compute
#pragma unroll
        for (int ki = 0; ki < 2; ++ki) {
            f16x8 af[4], bf[NJ];
#pragma unroll
            for (int mi = 0; mi < 4; ++mi) {
                int row = wrow + mi * 16 + l15;
                af[mi] = *(const f16x8*)(As + row * 128 + (((ki * 4 + l4) << 4) ^ pa));
            }
#pragma unroll
            for (int nj = 0; nj < NJ; ++nj) {
                int row = wcol + nj * 16 + l15;
                bf[nj] = *(const f16x8*)(Bs + row * 128 + (((ki * 4 + l4) << 4) ^ pa));
            }
            __builtin_amdgcn_s_setprio(1);
#pragma unroll
            for (int mi = 0; mi < 4; ++mi)
#pragma unroll
                for (int nj = 0; nj < NJ; ++nj)
                    acc[mi][nj] = MFMA_F16(af[mi], bf[nj], acc[mi][nj]);
            __builtin_amdgcn_s_setprio(0);
        }
    }

    // ---- epilogue ----
#pragma unroll
    for (int mi = 0; mi < 4; ++mi) {
#pragma unroll
        for (int nj = 0; nj < NJ; ++nj) {
#pragma unroll
            for (int reg = 0; reg < 4; ++reg) {
                int grow = bm0 + wrow + mi * 16 + l4 * 4 + reg;
                int gcol = bn0 + wcol + nj * 16 + l15;
                float val = acc[mi][nj][reg];
                if (EPI == 1) {
                    int t = gcol >> 8, h = (gcol >> 5) & 7, dd = gcol & 31;
                    int b = grow >> 12, n = grow & 4095;
                    int blk = n >> 8, r = n & 255;
                    size_t idx = (size_t)t * 4194304 +
                                 (size_t)((((b << 3) + h) << 4) + blk) * 8192 +
                                 (size_t)r * 32 + dd;
                    ((half_t*)Dst)[idx] = (half_t)val;
                } else {
                    ((float*)Dst)[(size_t)grow * 512 + gcol] = val + bias[gcol];
                }
            }
        }
    }
}

// ---------------------------------------------------------------------------
// Block-diagonal attention (R15-proven). One 512-thread WG per (b,h,blk):
// 8 waves, each owns 32 q rows. V^T staged once into LDS [dd][key] pad 264.
// Swapped QK^T; q pre-scaled by 0.125*log2e -> P = exp2(S); one final div.
// ---------------------------------------------------------------------------
__global__ __launch_bounds__(512, 4) void attn_f16(const half_t* __restrict__ qkv_ws,
                                                   half_t* __restrict__ o_ws) {
    __shared__ __align__(16) half_t VT[32 * 264];  // [dd][key], 16.5 KB

    const int blkid = blockIdx.x;            // (b*8+h)*16+blk
    const int b = blkid >> 7, h = (blkid >> 4) & 7, blk = blkid & 15;
    const half_t* Q  = qkv_ws + (size_t)blkid * 8192;
    const half_t* Kp = qkv_ws + 4194304 + (size_t)blkid * 8192;
    const half_t* V  = qkv_ws + 8388608 + (size_t)blkid * 8192;  // [key][dd]

    const int tid = threadIdx.x, lane = tid & 63, w = tid >> 6;
    const int l15 = lane & 15, l4 = lane >> 4;
    const int qb = w * 32;

#pragma unroll
    for (int i = 0; i < 2; ++i) {
        int c = tid + i * 512;
        int key = c >> 2, k8 = (c & 3) * 8;
        f16x8 v = *(const f16x8*)(V + key * 32 + k8);
#pragma unroll
        for (int e = 0; e < 8; ++e) VT[(k8 + e) * 264 + key] = v[e];
    }

    f16x8 aq[2];
    aq[0] = *(const f16x8*)(Q + (qb + l15) * 32 + l4 * 8);
    aq[1] = *(const f16x8*)(Q + (qb + 16 + l15) * 32 + l4 * 8);

    __syncthreads();

    float s_run[2] = {0.f, 0.f};
    f32x4 acc_o[2][2];
#pragma unroll
    for (int qg = 0; qg < 2; ++qg)
#pragma unroll
        for (int fo = 0; fo < 2; ++fo) acc_o[qg][fo] = (f32x4){0.f, 0.f, 0.f, 0.f};
    const f32x4 zero4 = (f32x4){0.f, 0.f, 0.f, 0.f};

    for (int kt = 0; kt < 4; ++kt) {
        f16x8 ka[4];
#pragma unroll
        for (int t = 0; t < 4; ++t)
            ka[t] = *(const f16x8*)(Kp + (kt * 64 + t * 16 + l15) * 32 + l4 * 8);
        f16x8 bv[2][2];
#pragma unroll
        for (int c = 0; c < 2; ++c)
#pragma unroll
            for (int fo = 0; fo < 2; ++fo)
                bv[c][fo] = *(const f16x8*)&VT[(fo * 16 + l15) * 264 + kt * 64 + c * 32 + l4 * 8];

        f32x4 st[2][4];
        __builtin_amdgcn_s_setprio(1);
#pragma unroll
        for (int qg = 0; qg < 2; ++qg)
#pragma unroll
            for (int t = 0; t < 4; ++t) st[qg][t] = MFMA_F16(ka[t], aq[qg], zero4);
        __builtin_amdgcn_s_setprio(0);

#pragma unroll
        for (int qg = 0; qg < 2; ++qg) {
            float p[4][4];
            float ps = 0.f;
#pragma unroll
            for (int t = 0; t < 4; ++t)
#pragma unroll
                for (int r = 0; r < 4; ++r) {
                    float e = exp2f(st[qg][t][r]);
                    p[t][r] = e;
                    ps += e;
                }
            ps += __shfl_xor(ps, 16);
            ps += __shfl_xor(ps, 32);
            s_run[qg] += ps;

#pragma unroll
            for (int c = 0; c < 2; ++c) {
                unsigned pk0[2], pk1[2];
#pragma unroll
                for (int rp = 0; rp < 2; ++rp) {
                    pk0[rp] = pkrtz(p[2 * c][2 * rp], p[2 * c][2 * rp + 1]);
                    pk1[rp] = pkrtz(p[2 * c + 1][2 * rp], p[2 * c + 1][2 * rp + 1]);
                }
                union { unsigned u[4]; f16x8 v; } au;
#pragma unroll
                for (int j = 0; j < 4; ++j) {
                    int src = l15 + ((((l4 & 1) << 1) + (j >> 1)) << 4);
                    unsigned g0 = (unsigned)__shfl((int)pk0[j & 1], src);
                    unsigned g1 = (unsigned)__shfl((int)pk1[j & 1], src);
                    au.u[j] = (l4 < 2) ? g0 : g1;
                }
                __builtin_amdgcn_s_setprio(1);
#pragma unroll
                for (int fo = 0; fo < 2; ++fo)
                    acc_o[qg][fo] = MFMA_F16(au.v, bv[c][fo], acc_o[qg][fo]);
                __builtin_amdgcn_s_setprio(0);
            }
        }
    }

#pragma unroll
    for (int qg = 0; qg < 2; ++qg) {
        float inv = 1.f / s_run[qg];
        float sinv[4];
#pragma unroll
        for (int r = 0; r < 4; ++r) sinv[r] = __shfl(inv, (l4 << 2) | r);
#pragma unroll
        for (int fo = 0; fo < 2; ++fo)
#pragma unroll
            for (int r = 0; r < 4; ++r) {
                int grow = b * 4096 + blk * 256 + qb + qg * 16 + l4 * 4 + r;
                o_ws[(size_t)grow * 256 + h * 32 + fo * 16 + l15] =
                    (half_t)(acc_o[qg][fo][r] * sinv[r]);
            }
    }
}

// ---------------------------------------------------------------------------
extern "C" void kernel_launch(void* const* d_in, const int* in_sizes, int n_in,
                              void* d_out, int out_size, void* d_ws, size_t ws_size,
                              hipStream_t stream) {
    const float* x        = (const float*)d_in[0];
    const float* reduce_w = (const float*)d_in[1];
    const float* qkv_w    = (const float*)d_in[2];
    const float* proj_w   = (const float*)d_in[3];
    const float* proj_b   = (const float*)d_in[4];
    char* ws = (char*)d_ws;

    half_t* qkv_ws = (half_t*)ws;                      // 3 x 4,194,304 halves
    half_t* o_buf  = (half_t*)(ws + 25165824);         // o [16384][256]
    half_t* pw_t   = (half_t*)(ws + 33554432);         // proj_w^T [512][256]
    half_t* Wt     = (half_t*)(ws + 33816576);         // (rw@qw)^T [768][512]

    // prep: Wt-GEMM (48) + pw_t (32)
    prep<<<80, 256, 0, stream>>>(qkv_w, reduce_w, proj_w, pw_t, Wt);
    // qkv = x @ W (fp32 A, reg-cvt), BM=128 BN=192, dbuf 80KB, 1 barrier/kt
    gemm_f16<1, true, 192, 512><<<dim3(128, 4), 512, 0, stream>>>(x, Wt, qkv_ws, nullptr);
    // block-diagonal attention: 512 WGs x 512 threads
    attn_f16<<<512, 512, 0, stream>>>(qkv_ws, o_buf);
    // out = o @ proj_w + proj_b, BM=128 BN=128, dbuf 64KB, 1 barrier/kt
    gemm_f16<2, false, 128, 256><<<dim3(128, 4), 512, 0, stream>>>(o_buf, pw_t, d_out, proj_b);
}

// Round 23
// 61.345 us; speedup vs baseline: 1.0930x; 1.0930x over previous
//
#include <hip/hip_runtime.h>
#include <hip/hip_fp16.h>

typedef _Float16 half_t;
typedef _Float16 f16x8 __attribute__((ext_vector_type(8)));
typedef __fp16 fp16x2 __attribute__((ext_vector_type(2)));
typedef float f32x4 __attribute__((ext_vector_type(4)));

#define MFMA_F16(a, b, c) __builtin_amdgcn_mfma_f32_16x16x32_f16((a), (b), (c), 0, 0, 0)

static __device__ inline unsigned pkrtz(float a, float b) {
    union { fp16x2 h; unsigned u; } c;
    c.h = __builtin_amdgcn_cvt_pkrtz(a, b);
    return c.u;
}

// ---------------------------------------------------------------------------
// prep (80 blocks):
//   0..47 : Wt = (rw@qw)^T fp16 [768][512]; q-cols scaled by 0.125*log2(e)
//   48..79: pw_t = proj_w^T fp16 [512][256]
// ---------------------------------------------------------------------------
__global__ __launch_bounds__(256) void prep(
    const float* __restrict__ qw, const float* __restrict__ rw,
    const float* __restrict__ pw, half_t* __restrict__ pw_t,
    half_t* __restrict__ Wt) {
    __shared__ __align__(16) char smem[24576];
    const int bid = blockIdx.x, tid = threadIdx.x;

    if (bid < 48) {
        char* As = smem;
        char* Bs = smem + 8192;
        const int M0 = (bid % 12) * 64, N0 = (bid / 12) * 128;
        const int lane = tid & 63, w = tid >> 6;
        const int l15 = lane & 15, l4 = lane >> 4;
        const int wrow = (w >> 1) * 32, wcol = (w & 1) * 64;
        const int pa = (l15 & 7) << 4;

        f32x4 acc[2][4];
#pragma unroll
        for (int i = 0; i < 2; ++i)
#pragma unroll
            for (int j = 0; j < 4; ++j) acc[i][j] = (f32x4){0.f, 0.f, 0.f, 0.f};

        for (int kc = 0; kc < 4; ++kc) {
            int c0 = kc * 64;
            __syncthreads();
#pragma unroll
            for (int i = 0; i < 2; ++i) {
                int j = tid + i * 256;
                int row = j >> 3, e8 = (j & 7) * 8;
                float s = (M0 + row) < 256 ? 0.18033688f : 1.f;  // 0.125*log2e
                f16x8 v;
#pragma unroll
                for (int e = 0; e < 8; ++e)
                    v[e] = (half_t)(qw[(size_t)(c0 + e8 + e) * 768 + M0 + row] * s);
                *(f16x8*)(As + row * 128 + ((e8 * 2) ^ ((row & 7) << 4))) = v;
            }
#pragma unroll
            for (int i = 0; i < 4; ++i) {
                int j = tid + i * 256;
                int row = j >> 3, e8 = (j & 7) * 8;
                const float* p = rw + (size_t)(N0 + row) * 256 + c0 + e8;
                float4 u0 = *(const float4*)p;
                float4 u1 = *(const float4*)(p + 4);
                f16x8 v;
                v[0] = (half_t)u0.x; v[1] = (half_t)u0.y;
                v[2] = (half_t)u0.z; v[3] = (half_t)u0.w;
                v[4] = (half_t)u1.x; v[5] = (half_t)u1.y;
                v[6] = (half_t)u1.z; v[7] = (half_t)u1.w;
                *(f16x8*)(Bs + row * 128 + ((e8 * 2) ^ ((row & 7) << 4))) = v;
            }
            __syncthreads();
#pragma unroll
            for (int ki = 0; ki < 2; ++ki) {
                f16x8 af[2], bf[4];
#pragma unroll
                for (int mi = 0; mi < 2; ++mi) {
                    int row = wrow + mi * 16 + l15;
                    af[mi] = *(const f16x8*)(As + row * 128 + (((ki * 4 + l4) << 4) ^ pa));
                }
#pragma unroll
                for (int nj = 0; nj < 4; ++nj) {
                    int row = wcol + nj * 16 + l15;
                    bf[nj] = *(const f16x8*)(Bs + row * 128 + (((ki * 4 + l4) << 4) ^ pa));
                }
#pragma unroll
                for (int mi = 0; mi < 2; ++mi)
#pragma unroll
                    for (int nj = 0; nj < 4; ++nj)
                        acc[mi][nj] = MFMA_F16(af[mi], bf[nj], acc[mi][nj]);
            }
        }
#pragma unroll
        for (int mi = 0; mi < 2; ++mi)
#pragma unroll
            for (int nj = 0; nj < 4; ++nj)
#pragma unroll
                for (int reg = 0; reg < 4; ++reg) {
                    int grow = M0 + wrow + mi * 16 + l4 * 4 + reg;
                    int gcol = N0 + wcol + nj * 16 + l15;
                    Wt[(size_t)grow * 512 + gcol] = (half_t)acc[mi][nj][reg];
                }
        return;
    }

    // pw transpose
    half_t* tile = (half_t*)smem;  // [64][72]
    int t = bid - 48;
    int R0 = (t >> 3) * 64, C0 = (t & 7) * 64;
#pragma unroll
    for (int e = 0; e < 16; ++e) {
        int idx = tid + e * 256;
        int r = idx >> 6, c = idx & 63;
        tile[r * 72 + c] = (half_t)pw[(size_t)(R0 + r) * 512 + C0 + c];
    }
    __syncthreads();
#pragma unroll
    for (int e = 0; e < 16; ++e) {
        int idx = tid + e * 256;
        int c = idx >> 6, r = idx & 63;
        pw_t[(size_t)(C0 + c) * 256 + R0 + r] = tile[r * 72 + c];
    }
}

// ---------------------------------------------------------------------------
// fp16 MFMA GEMM, 8-wave high-occupancy engine (best measured config),
// wave grid 2M x 4N (wave tile 64 x NB/4). BM=128, BN=NB, BK=64, 512 thr.
// Single LDS set (16KB + NB*128B), reg-staged prefetch, plain syncthreads.
// K-loop fully unrolled.
// AFP32: A read fp32 + RTE cvt in reg.
// EPI 1: scatter q/k/v row-major [t][blk][key][dd]
// EPI 2: float out[grow*512+gcol] = acc + bias[gcol]
// ---------------------------------------------------------------------------
template <int EPI, bool AFP32, int NB, int K>
__global__ __launch_bounds__(512) void gemm_f16(
    const void* __restrict__ Aop, const half_t* __restrict__ Bt,
    void* __restrict__ Dst, const float* __restrict__ bias) {
    constexpr int nkt = K >> 6;
    constexpr int NAC = 2;         // A chunks per thread
    constexpr int NBC = NB / 64;   // B chunks per thread
    constexpr int NJ = NB / 64;    // B frags per wave
    __shared__ __align__(16) char smem[16384 + NB * 128];
    char* As = smem;
    char* Bs = smem + 16384;

    const int tid = threadIdx.x;
    const int lane = tid & 63, w = tid >> 6;
    const int l15 = lane & 15, l4 = lane >> 4;
    const int wrow = (w >> 2) * 64;
    const int wcol = (w & 3) * (NB / 4);
    const int bm0 = blockIdx.x * 128;
    const int bn0 = blockIdx.y * NB;
    const int pa = (l15 & 7) << 4;

    f32x4 acc[4][NJ];
#pragma unroll
    for (int i = 0; i < 4; ++i)
#pragma unroll
        for (int j = 0; j < NJ; ++j) acc[i][j] = (f32x4){0.f, 0.f, 0.f, 0.f};

    f16x8 aReg[NAC], bReg[NBC];

    auto load_tile = [&](int kt) {
#pragma unroll
        for (int i = 0; i < NAC; ++i) {
            int c = tid + i * 512;
            int row = c >> 3, k0 = (c & 7) * 8;
            int gk = kt * 64 + k0;
            if (AFP32) {
                const float* Af = (const float*)Aop + (size_t)(bm0 + row) * K + gk;
                float4 u0 = *(const float4*)Af;
                float4 u1 = *(const float4*)(Af + 4);
                f16x8 v;
                v[0] = (half_t)u0.x; v[1] = (half_t)u0.y;
                v[2] = (half_t)u0.z; v[3] = (half_t)u0.w;
                v[4] = (half_t)u1.x; v[5] = (half_t)u1.y;
                v[6] = (half_t)u1.z; v[7] = (half_t)u1.w;
                aReg[i] = v;
            } else {
                aReg[i] = *(const f16x8*)((const half_t*)Aop + (size_t)(bm0 + row) * K + gk);
            }
        }
#pragma unroll
        for (int i = 0; i < NBC; ++i) {
            int c = tid + i * 512;
            int row = c >> 3, k0 = (c & 7) * 8;
            bReg[i] = *(const f16x8*)(Bt + (size_t)(bn0 + row) * K + kt * 64 + k0);
        }
    };

    load_tile(0);
#pragma unroll
    for (int kt = 0; kt < nkt; ++kt) {
        __syncthreads();
#pragma unroll
        for (int i = 0; i < NAC; ++i) {
            int c = tid + i * 512;
            int row = c >> 3, k0 = (c & 7) * 8;
            *(f16x8*)(As + row * 128 + ((k0 * 2) ^ ((row & 7) << 4))) = aReg[i];
        }
#pragma unroll
        for (int i = 0; i < NBC; ++i) {
            int c = tid + i * 512;
            int row = c >> 3, k0 = (c & 7) * 8;
            *(f16x8*)(Bs + row * 128 + ((k0 * 2) ^ ((row & 7) << 4))) = bReg[i];
        }
        __syncthreads();
        if (kt + 1 < nkt) load_tile(kt + 1);
#pragma unroll
        for (int ki = 0; ki < 2; ++ki) {
            f16x8 af[4], bf[NJ];
#pragma unroll
            for (int mi = 0; mi < 4; ++mi) {
                int row = wrow + mi * 16 + l15;
                af[mi] = *(const f16x8*)(As + row * 128 + (((ki * 4 + l4) << 4) ^ pa));
            }
#pragma unroll
            for (int nj = 0; nj < NJ; ++nj) {
                int row = wcol + nj * 16 + l15;
                bf[nj] = *(const f16x8*)(Bs + row * 128 + (((ki * 4 + l4) << 4) ^ pa));
            }
#pragma unroll
            for (int mi = 0; mi < 4; ++mi)
#pragma unroll
                for (int nj = 0; nj < NJ; ++nj)
                    acc[mi][nj] = MFMA_F16(af[mi], bf[nj], acc[mi][nj]);
        }
    }

    // ---- epilogue ----
#pragma unroll
    for (int mi = 0; mi < 4; ++mi) {
#pragma unroll
        for (int nj = 0; nj < NJ; ++nj) {
#pragma unroll
            for (int reg = 0; reg < 4; ++reg) {
                int grow = bm0 + wrow + mi * 16 + l4 * 4 + reg;
                int gcol = bn0 + wcol + nj * 16 + l15;
                float val = acc[mi][nj][reg];
                if (EPI == 1) {
                    int t = gcol >> 8, h = (gcol >> 5) & 7, dd = gcol & 31;
                    int b = grow >> 12, n = grow & 4095;
                    int blk = n >> 8, r = n & 255;
                    size_t idx = (size_t)t * 4194304 +
                                 (size_t)((((b << 3) + h) << 4) + blk) * 8192 +
                                 (size_t)r * 32 + dd;
                    ((half_t*)Dst)[idx] = (half_t)val;
                } else {
                    ((float*)Dst)[(size_t)grow * 512 + gcol] = val + bias[gcol];
                }
            }
        }
    }
}

// ---------------------------------------------------------------------------
// Block-diagonal attention. One 512-thread WG per (b,h,blk): 8 waves, each
// owns 32 q rows. V^T staged once into LDS [dd][key] pad 264.
// Swapped QK^T; q pre-scaled by 0.125*log2e -> P = exp2(S); one final div.
// ---------------------------------------------------------------------------
__global__ __launch_bounds__(512, 4) void attn_f16(const half_t* __restrict__ qkv_ws,
                                                   half_t* __restrict__ o_ws) {
    __shared__ __align__(16) half_t VT[32 * 264];  // [dd][key], 16.5 KB

    const int blkid = blockIdx.x;            // (b*8+h)*16+blk
    const int b = blkid >> 7, h = (blkid >> 4) & 7, blk = blkid & 15;
    const half_t* Q  = qkv_ws + (size_t)blkid * 8192;
    const half_t* Kp = qkv_ws + 4194304 + (size_t)blkid * 8192;
    const half_t* V  = qkv_ws + 8388608 + (size_t)blkid * 8192;  // [key][dd]

    const int tid = threadIdx.x, lane = tid & 63, w = tid >> 6;
    const int l15 = lane & 15, l4 = lane >> 4;
    const int qb = w * 32;

#pragma unroll
    for (int i = 0; i < 2; ++i) {
        int c = tid + i * 512;
        int key = c >> 2, k8 = (c & 3) * 8;
        f16x8 v = *(const f16x8*)(V + key * 32 + k8);
#pragma unroll
        for (int e = 0; e < 8; ++e) VT[(k8 + e) * 264 + key] = v[e];
    }

    f16x8 aq[2];
    aq[0] = *(const f16x8*)(Q + (qb + l15) * 32 + l4 * 8);
    aq[1] = *(const f16x8*)(Q + (qb + 16 + l15) * 32 + l4 * 8);

    __syncthreads();

    float s_run[2] = {0.f, 0.f};
    f32x4 acc_o[2][2];
#pragma unroll
    for (int qg = 0; qg < 2; ++qg)
#pragma unroll
        for (int fo = 0; fo < 2; ++fo) acc_o[qg][fo] = (f32x4){0.f, 0.f, 0.f, 0.f};
    const f32x4 zero4 = (f32x4){0.f, 0.f, 0.f, 0.f};

    for (int kt = 0; kt < 4; ++kt) {
        f16x8 ka[4];
#pragma unroll
        for (int t = 0; t < 4; ++t)
            ka[t] = *(const f16x8*)(Kp + (kt * 64 + t * 16 + l15) * 32 + l4 * 8);
        f16x8 bv[2][2];
#pragma unroll
        for (int c = 0; c < 2; ++c)
#pragma unroll
            for (int fo = 0; fo < 2; ++fo)
                bv[c][fo] = *(const f16x8*)&VT[(fo * 16 + l15) * 264 + kt * 64 + c * 32 + l4 * 8];

        f32x4 st[2][4];
        __builtin_amdgcn_s_setprio(1);
#pragma unroll
        for (int qg = 0; qg < 2; ++qg)
#pragma unroll
            for (int t = 0; t < 4; ++t) st[qg][t] = MFMA_F16(ka[t], aq[qg], zero4);
        __builtin_amdgcn_s_setprio(0);

#pragma unroll
        for (int qg = 0; qg < 2; ++qg) {
            float p[4][4];
            float ps = 0.f;
#pragma unroll
            for (int t = 0; t < 4; ++t)
#pragma unroll
                for (int r = 0; r < 4; ++r) {
                    float e = exp2f(st[qg][t][r]);
                    p[t][r] = e;
                    ps += e;
                }
            ps += __shfl_xor(ps, 16);
            ps += __shfl_xor(ps, 32);
            s_run[qg] += ps;

#pragma unroll
            for (int c = 0; c < 2; ++c) {
                unsigned pk0[2], pk1[2];
#pragma unroll
                for (int rp = 0; rp < 2; ++rp) {
                    pk0[rp] = pkrtz(p[2 * c][2 * rp], p[2 * c][2 * rp + 1]);
                    pk1[rp] = pkrtz(p[2 * c + 1][2 * rp], p[2 * c + 1][2 * rp + 1]);
                }
                union { unsigned u[4]; f16x8 v; } au;
#pragma unroll
                for (int j = 0; j < 4; ++j) {
                    int src = l15 + ((((l4 & 1) << 1) + (j >> 1)) << 4);
                    unsigned g0 = (unsigned)__shfl((int)pk0[j & 1], src);
                    unsigned g1 = (unsigned)__shfl((int)pk1[j & 1], src);
                    au.u[j] = (l4 < 2) ? g0 : g1;
                }
                __builtin_amdgcn_s_setprio(1);
#pragma unroll
                for (int fo = 0; fo < 2; ++fo)
                    acc_o[qg][fo] = MFMA_F16(au.v, bv[c][fo], acc_o[qg][fo]);
                __builtin_amdgcn_s_setprio(0);
            }
        }
    }

#pragma unroll
    for (int qg = 0; qg < 2; ++qg) {
        float inv = 1.f / s_run[qg];
        float sinv[4];
#pragma unroll
        for (int r = 0; r < 4; ++r) sinv[r] = __shfl(inv, (l4 << 2) | r);
#pragma unroll
        for (int fo = 0; fo < 2; ++fo)
#pragma unroll
            for (int r = 0; r < 4; ++r) {
                int grow = b * 4096 + blk * 256 + qb + qg * 16 + l4 * 4 + r;
                o_ws[(size_t)grow * 256 + h * 32 + fo * 16 + l15] =
                    (half_t)(acc_o[qg][fo][r] * sinv[r]);
            }
    }
}

// ---------------------------------------------------------------------------
extern "C" void kernel_launch(void* const* d_in, const int* in_sizes, int n_in,
                              void* d_out, int out_size, void* d_ws, size_t ws_size,
                              hipStream_t stream) {
    const float* x        = (const float*)d_in[0];
    const float* reduce_w = (const float*)d_in[1];
    const float* qkv_w    = (const float*)d_in[2];
    const float* proj_w   = (const float*)d_in[3];
    const float* proj_b   = (const float*)d_in[4];
    char* ws = (char*)d_ws;

    half_t* qkv_ws = (half_t*)ws;                      // 3 x 4,194,304 halves
    half_t* o_buf  = (half_t*)(ws + 25165824);         // o [16384][256]
    half_t* pw_t   = (half_t*)(ws + 33554432);         // proj_w^T [512][256]
    half_t* Wt     = (half_t*)(ws + 33816576);         // (rw@qw)^T [768][512]

    // prep: Wt-GEMM (48) + pw_t (32)
    prep<<<80, 256, 0, stream>>>(qkv_w, reduce_w, proj_w, pw_t, Wt);
    // qkv = x @ W (fp32 A, reg-cvt), M=16384 N=768 K=512, BM=128 BN=192,
    // 512 WGs x 512 thr @ 40KB LDS, wave grid 2Mx4N
    gemm_f16<1, true, 192, 512><<<dim3(128, 4), 512, 0, stream>>>(x, Wt, qkv_ws, nullptr);
    // block-diagonal attention: 512 WGs x 512 threads, V^T staged in LDS
    attn_f16<<<512, 512, 0, stream>>>(qkv_ws, o_buf);
    // out = o @ proj_w + proj_b, M=16384 N=512 K=256, BM=128 BN=256,
    // 256 WGs x 512 thr @ 48KB LDS, wave grid 2Mx4N
    gemm_f16<2, false, 256, 256><<<dim3(128, 2), 512, 0, stream>>>(o_buf, pw_t, d_out, proj_b);
}